// Round 11
// baseline (68.802 us; speedup 1.0000x reference)
//
#include <hip/hip_runtime.h>
#include <float.h>
#include <math.h>

// B=65536 rows, C=1000 cols, fp32. R11 = R10 (contiguous 8 rows/wave) with
// TWO-ROW ILP: rows processed as 4 interleaved pairs. Diagnosis (R10 pm):
// 2375 cyc/row/SIMD observed vs ~640 issue-cycles -> serial-latency-bound
// (19 serial DS-shuffle exposures + exp chains per row, only 4 waves/SIMD).
// Pair-interleaving halves the per-row critical path: one 6-step butterfly
// reduces both rows' values (2-wide max, 6-wide sum, 2-wide S2).
// Per row: pass1 m,L; pass2 S,W; T=clip(softplus(L+wH*Hhat/lnC+b),EPS);
// pass3 S2; nll = logS2 - (x_lab - m)/T.  Mean in double via partials.

static constexpr int   kC4    = 250;   // float4 per row (1000 floats)
static constexpr int   kBlock = 256;   // 4 waves per block
static constexpr int   kGrid  = 2048;  // 8192 waves
static constexpr int   kWavesTotal = kGrid * (kBlock / 64);
static constexpr int   kRPW   = 8;     // rows per wave (contiguous chunk)
static constexpr int   kPairs = kRPW / 2;
static constexpr float kEps   = 1.1920928955078125e-07f;  // FLT_EPSILON
static constexpr float kLogC  = 6.907755279f;             // ln(1000)

__device__ __forceinline__ float wred_max(float v) {
#pragma unroll
  for (int off = 32; off > 0; off >>= 1) v = fmaxf(v, __shfl_xor(v, off, 64));
  return v;
}
__device__ __forceinline__ float wred_sum(float v) {
#pragma unroll
  for (int off = 32; off > 0; off >>= 1) v += __shfl_xor(v, off, 64);
  return v;
}
__device__ __forceinline__ void wred_max2(float& a, float& b) {
#pragma unroll
  for (int off = 32; off > 0; off >>= 1) {
    const float ta = __shfl_xor(a, off, 64);
    const float tb = __shfl_xor(b, off, 64);
    a = fmaxf(a, ta); b = fmaxf(b, tb);
  }
}
__device__ __forceinline__ void wred_sum2(float& a, float& b) {
#pragma unroll
  for (int off = 32; off > 0; off >>= 1) {
    const float ta = __shfl_xor(a, off, 64);
    const float tb = __shfl_xor(b, off, 64);
    a += ta; b += tb;
  }
}
__device__ __forceinline__ void wred_sum6(float& a, float& b, float& c,
                                          float& d, float& e, float& f) {
#pragma unroll
  for (int off = 32; off > 0; off >>= 1) {
    const float ta = __shfl_xor(a, off, 64);
    const float tb = __shfl_xor(b, off, 64);
    const float tc = __shfl_xor(c, off, 64);
    const float td = __shfl_xor(d, off, 64);
    const float te = __shfl_xor(e, off, 64);
    const float tf = __shfl_xor(f, off, 64);
    a += ta; b += tb; c += tc; d += td; e += te; f += tf;
  }
}

__device__ __forceinline__ void p1_dot_max(const float4 c, const float4 w,
                                           float& L, float& m) {
  L = fmaf(c.x, w.x, L); L = fmaf(c.y, w.y, L);
  L = fmaf(c.z, w.z, L); L = fmaf(c.w, w.w, L);
  m = fmaxf(m, fmaxf(fmaxf(c.x, c.y), fmaxf(c.z, c.w)));
}
__device__ __forceinline__ void p2_sumexp(const float4 c, const float m,
                                          float& S, float& W) {
  float e;
  e = __expf(c.x - m); S += e; W = fmaf(e, c.x, W);
  e = __expf(c.y - m); S += e; W = fmaf(e, c.y, W);
  e = __expf(c.z - m); S += e; W = fmaf(e, c.z, W);
  e = __expf(c.w - m); S += e; W = fmaf(e, c.w, W);
}
__device__ __forceinline__ void p3_sumexp2(const float4 c, const float rT,
                                           const float nmrT, float& S2) {
  S2 += __expf(fmaf(c.x, rT, nmrT)); S2 += __expf(fmaf(c.y, rT, nmrT));
  S2 += __expf(fmaf(c.z, rT, nmrT)); S2 += __expf(fmaf(c.w, rT, nmrT));
}
__device__ __forceinline__ float pick_lab(const float4 v, const int el) {
  return (el == 0) ? v.x : (el == 1) ? v.y : (el == 2) ? v.z : v.w;
}

#define SENT4 make_float4(-FLT_MAX, -FLT_MAX, -FLT_MAX, -FLT_MAX)

// ---- specialized: B == kWavesTotal * kRPW, contiguous chunks, pair-ILP ----
__global__ __launch_bounds__(kBlock) void ats_row_kernel_p2(
    const float* __restrict__ X, const int* __restrict__ labels,
    const float* __restrict__ wL, const float* __restrict__ wH,
    const float* __restrict__ bb, double* __restrict__ partial) {
  const int lane   = threadIdx.x & 63;
  const int wib    = threadIdx.x >> 6;
  const int wid    = blockIdx.x * (kBlock / 64) + wib;
  const bool tailok = lane < (kC4 - 192);

  const float4* WLr = reinterpret_cast<const float4*>(wL);
  const float4 w0 = WLr[lane];
  const float4 w1 = WLr[64 + lane];
  const float4 w2 = WLr[128 + lane];
  const float4 w3 = tailok ? WLr[192 + lane] : make_float4(0.f, 0.f, 0.f, 0.f);
  const float wH0 = wH[0];
  const float b0  = bb[0];

  double acc = 0.0;
  const int base = wid * kRPW;

  // pair 0 load
  float4 a0, a1, a2, a3, c0, c1, c2, c3;
  int laba, labb;
  {
    const float4* Xa = reinterpret_cast<const float4*>(X) + (size_t)base * kC4;
    const float4* Xb = Xa + kC4;
    a0 = Xa[lane]; a1 = Xa[64 + lane]; a2 = Xa[128 + lane];
    a3 = tailok ? Xa[192 + lane] : SENT4;
    c0 = Xb[lane]; c1 = Xb[64 + lane]; c2 = Xb[128 + lane];
    c3 = tailok ? Xb[192 + lane] : SENT4;
    laba = labels[base];
    labb = labels[base + 1];
  }

  for (int p = 0; p < kPairs; ++p) {
    // ---- prefetch next pair (conditional, R3/R10 style — do not clamp)
    float4 na0 = SENT4, na1 = SENT4, na2 = SENT4, na3 = SENT4;
    float4 nb0 = SENT4, nb1 = SENT4, nb2 = SENT4, nb3 = SENT4;
    int nlaba = 0, nlabb = 0;
    if (p + 1 < kPairs) {
      const int r = base + 2 * (p + 1);
      const float4* Xa = reinterpret_cast<const float4*>(X) + (size_t)r * kC4;
      const float4* Xb = Xa + kC4;
      na0 = Xa[lane]; na1 = Xa[64 + lane]; na2 = Xa[128 + lane];
      na3 = tailok ? Xa[192 + lane] : SENT4;
      nb0 = Xb[lane]; nb1 = Xb[64 + lane]; nb2 = Xb[128 + lane];
      nb3 = tailok ? Xb[192 + lane] : SENT4;
      nlaba = labels[r];
      nlabb = labels[r + 1];
    }

    // ---- pass1 interleaved: per-lane max + dot for both rows
    float La = 0.f, ma = -FLT_MAX, Lb = 0.f, mb = -FLT_MAX;
    p1_dot_max(a0, w0, La, ma); p1_dot_max(c0, w0, Lb, mb);
    p1_dot_max(a1, w1, La, ma); p1_dot_max(c1, w1, Lb, mb);
    p1_dot_max(a2, w2, La, ma); p1_dot_max(c2, w2, Lb, mb);
    p1_dot_max(a3, w3, La, ma); p1_dot_max(c3, w3, Lb, mb);
    wred_max2(ma, mb);  // one 6-step butterfly, both rows

    // ---- pass2 interleaved
    float Sa = 0.f, Wa = 0.f, Sb = 0.f, Wb = 0.f;
    p2_sumexp(a0, ma, Sa, Wa); p2_sumexp(c0, mb, Sb, Wb);
    p2_sumexp(a1, ma, Sa, Wa); p2_sumexp(c1, mb, Sb, Wb);
    p2_sumexp(a2, ma, Sa, Wa); p2_sumexp(c2, mb, Sb, Wb);
    p2_sumexp(a3, ma, Sa, Wa); p2_sumexp(c3, mb, Sb, Wb);
    wred_sum6(Sa, Wa, La, Sb, Wb, Lb);  // one 6-step butterfly, 6 values

    // ---- x[label] for both rows (labels wave-uniform -> one shfl each)
    const int c4a = laba >> 2, c4b = labb >> 2;
    const int sla = c4a >> 6, lna = c4a & 63, ela = laba & 3;
    const int slb = c4b >> 6, lnb = c4b & 63, elb = labb & 3;
    float4 va = (sla == 0) ? a0 : (sla == 1) ? a1 : (sla == 2) ? a2 : a3;
    float4 vb = (slb == 0) ? c0 : (slb == 1) ? c1 : (slb == 2) ? c2 : c3;
    const float xla = __shfl(pick_lab(va, ela), lna, 64);
    const float xlb = __shfl(pick_lab(vb, elb), lnb, 64);

    // ---- temperatures
    const float Ha = Wa / Sa - ma - __logf(Sa);
    const float Hb = Wb / Sb - mb - __logf(Sb);
    const float aa = La + wH0 * (Ha / kLogC) + b0;
    const float ab = Lb + wH0 * (Hb / kLogC) + b0;
    const float spa = (aa > 0.f) ? (aa + log1pf(__expf(-aa))) : log1pf(__expf(aa));
    const float spb = (ab > 0.f) ? (ab + log1pf(__expf(-ab))) : log1pf(__expf(ab));
    const float Ta = fmaxf(spa, kEps), Tb = fmaxf(spb, kEps);
    const float rTa = 1.0f / Ta, rTb = 1.0f / Tb;
    const float nma = -ma * rTa, nmb = -mb * rTb;

    // ---- pass3 interleaved
    float S2a = 0.f, S2b = 0.f;
    p3_sumexp2(a0, rTa, nma, S2a); p3_sumexp2(c0, rTb, nmb, S2b);
    p3_sumexp2(a1, rTa, nma, S2a); p3_sumexp2(c1, rTb, nmb, S2b);
    p3_sumexp2(a2, rTa, nma, S2a); p3_sumexp2(c2, rTb, nmb, S2b);
    p3_sumexp2(a3, rTa, nma, S2a); p3_sumexp2(c3, rTb, nmb, S2b);
    wred_sum2(S2a, S2b);

    const float nlla = __logf(S2a) - fmaf(xla, rTa, nma);
    const float nllb = __logf(S2b) - fmaf(xlb, rTb, nmb);
    acc += (double)(nlla + nllb);

    // ---- rotate pair pipeline
    a0 = na0; a1 = na1; a2 = na2; a3 = na3;
    c0 = nb0; c1 = nb1; c2 = nb2; c3 = nb3;
    laba = nlaba; labb = nlabb;
  }

  __shared__ double sacc[kBlock / 64];
  if (lane == 0) sacc[wib] = acc;
  __syncthreads();
  if (threadIdx.x == 0)
    partial[blockIdx.x] = (sacc[0] + sacc[1]) + (sacc[2] + sacc[3]);
}

// ---- generic fallback: R3 mapping, one row at a time ---------------------
__device__ __forceinline__ float row_nll(
    const float4 c0, const float4 c1, const float4 c2, const float4 c3,
    const float4 w0, const float4 w1, const float4 w2, const float4 w3,
    const int labc, const float wH0, const float b0) {
  float L = 0.f, m = -FLT_MAX;
  p1_dot_max(c0, w0, L, m); p1_dot_max(c1, w1, L, m);
  p1_dot_max(c2, w2, L, m); p1_dot_max(c3, w3, L, m);
  m = wred_max(m);
  float S = 0.f, W = 0.f;
  p2_sumexp(c0, m, S, W); p2_sumexp(c1, m, S, W);
  p2_sumexp(c2, m, S, W); p2_sumexp(c3, m, S, W);
  S = wred_sum(S); W = wred_sum(W); L = wred_sum(L);
  const int c4l = labc >> 2;
  const int sl = c4l >> 6, ln = c4l & 63, el = labc & 3;
  float4 v = (sl == 0) ? c0 : (sl == 1) ? c1 : (sl == 2) ? c2 : c3;
  const float xl = __shfl(pick_lab(v, el), ln, 64);
  const float Hhat = W / S - m - __logf(S);
  const float a = L + wH0 * (Hhat / kLogC) + b0;
  const float sp = (a > 0.f) ? (a + log1pf(__expf(-a))) : log1pf(__expf(a));
  const float T = fmaxf(sp, kEps);
  const float rT = 1.0f / T, nmrT = -m * rT;
  float S2 = 0.f;
  p3_sumexp2(c0, rT, nmrT, S2); p3_sumexp2(c1, rT, nmrT, S2);
  p3_sumexp2(c2, rT, nmrT, S2); p3_sumexp2(c3, rT, nmrT, S2);
  S2 = wred_sum(S2);
  return __logf(S2) - fmaf(xl, rT, nmrT);
}

__global__ __launch_bounds__(kBlock) void ats_row_kernel_gen(
    const float* __restrict__ X, const int* __restrict__ labels,
    const float* __restrict__ wL, const float* __restrict__ wH,
    const float* __restrict__ bb, double* __restrict__ partial, int B) {
  const int lane   = threadIdx.x & 63;
  const int wib    = threadIdx.x >> 6;
  const int wid    = blockIdx.x * (kBlock / 64) + wib;
  const bool tailok = lane < (kC4 - 192);

  const float4* WLr = reinterpret_cast<const float4*>(wL);
  const float4 w0 = WLr[lane];
  const float4 w1 = WLr[64 + lane];
  const float4 w2 = WLr[128 + lane];
  const float4 w3 = tailok ? WLr[192 + lane] : make_float4(0.f, 0.f, 0.f, 0.f);
  const float wH0 = wH[0];
  const float b0  = bb[0];

  double acc = 0.0;
  int row = wid;
  float4 c0, c1, c2, c3;
  int labc = 0;
  if (row < B) {
    const float4* Xr = reinterpret_cast<const float4*>(X) + (size_t)row * kC4;
    c0 = Xr[lane]; c1 = Xr[64 + lane]; c2 = Xr[128 + lane];
    c3 = tailok ? Xr[192 + lane] : SENT4;
    labc = labels[row];
  }
  for (; row < B; row += kWavesTotal) {
    const int nrow = row + kWavesTotal;
    float4 n0 = SENT4, n1 = SENT4, n2 = SENT4, n3 = SENT4;
    int labn = 0;
    if (nrow < B) {
      const float4* Xn = reinterpret_cast<const float4*>(X) + (size_t)nrow * kC4;
      n0 = Xn[lane]; n1 = Xn[64 + lane]; n2 = Xn[128 + lane];
      n3 = tailok ? Xn[192 + lane] : SENT4;
      labn = labels[nrow];
    }
    acc += (double)row_nll(c0, c1, c2, c3, w0, w1, w2, w3, labc, wH0, b0);
    c0 = n0; c1 = n1; c2 = n2; c3 = n3; labc = labn;
  }
  __shared__ double sacc[kBlock / 64];
  if (lane == 0) sacc[wib] = acc;
  __syncthreads();
  if (threadIdx.x == 0)
    partial[blockIdx.x] = (sacc[0] + sacc[1]) + (sacc[2] + sacc[3]);
}

__global__ __launch_bounds__(256) void ats_final_kernel(
    const double* __restrict__ partial, float* __restrict__ out, int n, int B) {
  __shared__ double sdata[256];
  double a = 0.0;
  for (int i = threadIdx.x; i < n; i += 256) a += partial[i];
  sdata[threadIdx.x] = a;
  __syncthreads();
#pragma unroll
  for (int s = 128; s > 0; s >>= 1) {
    if ((int)threadIdx.x < s) sdata[threadIdx.x] += sdata[threadIdx.x + s];
    __syncthreads();
  }
  if (threadIdx.x == 0) out[0] = (float)(sdata[0] / (double)B);
}

extern "C" void kernel_launch(void* const* d_in, const int* in_sizes, int n_in,
                              void* d_out, int out_size, void* d_ws, size_t ws_size,
                              hipStream_t stream) {
  (void)n_in; (void)out_size; (void)ws_size;
  const float* X   = (const float*)d_in[0];
  const int*   lab = (const int*)d_in[1];
  const float* wL  = (const float*)d_in[2];
  const float* wH  = (const float*)d_in[3];
  const float* bb  = (const float*)d_in[4];
  const int B = in_sizes[1];            // 65536 labels
  double* partial = (double*)d_ws;      // kGrid doubles = 16 KB scratch
  float* out = (float*)d_out;

  if (B == kWavesTotal * kRPW) {
    ats_row_kernel_p2<<<kGrid, kBlock, 0, stream>>>(X, lab, wL, wH, bb, partial);
  } else {
    ats_row_kernel_gen<<<kGrid, kBlock, 0, stream>>>(X, lab, wL, wH, bb,
                                                     partial, B);
  }
  ats_final_kernel<<<1, 256, 0, stream>>>(partial, out, kGrid, B);
}